// Round 6
// baseline (1539.270 us; speedup 1.0000x reference)
//
#include <hip/hip_runtime.h>
#include <hip/hip_bf16.h>
#include <stdint.h>

#define BETA 0.5f
#define IGNORE_INDEX (-100)

typedef short bf16x8 __attribute__((ext_vector_type(8)));
typedef float f32x4 __attribute__((ext_vector_type(4)));

// ---------------------------------------------------------------- converts
__global__ __launch_bounds__(256) void f32_to_bf16_kernel(
    const float* __restrict__ in, uint16_t* __restrict__ out, int n) {
  int i = (blockIdx.x * blockDim.x + threadIdx.x) * 4;
  const int stride = gridDim.x * blockDim.x * 4;
  for (; i < n; i += stride) {
    float4 v = *reinterpret_cast<const float4*>(in + i);
    __hip_bfloat16 b0 = __float2bfloat16(v.x);
    __hip_bfloat16 b1 = __float2bfloat16(v.y);
    __hip_bfloat16 b2 = __float2bfloat16(v.z);
    __hip_bfloat16 b3 = __float2bfloat16(v.w);
    ushort4 o;
    o.x = *reinterpret_cast<const uint16_t*>(&b0);
    o.y = *reinterpret_cast<const uint16_t*>(&b1);
    o.z = *reinterpret_cast<const uint16_t*>(&b2);
    o.w = *reinterpret_cast<const uint16_t*>(&b3);
    *reinterpret_cast<ushort4*>(out + i) = o;
  }
}

// ---------------------------------------------------------------- GEMM (NT)
// C[n][v] = sum_k A[n][k]*B[v][k].  256x256 tile, BK=64, 8 waves (2Mx4N).
// Register READ-AHEAD pipeline: each phase issues the NEXT phase's ds_reads
// before its own MFMA cluster (compiler emits counted lgkmcnt since DS is
// in-order) -> LDS service of phase p+1 overlaps MFMA of phase p.  ONE
// barrier per K-tile: lgkm(0)+vmcnt(0)+s_barrier at ph3, then stage(T+2)
// into the just-drained buffer and read-ahead of tile T+1 ph0, both
// overlapping MFMA(ph3).  2 LDS buffers x 64 KiB; stage depth 1 tile
// (~2600 cyc >> HBM latency).  setprio (T5), granule XOR swizzle
// both-sides (rule #21), XCD swizzle (T1).
// Merged launch: blocks [0,half) = teacher, [half,2*half) = student.

__global__ __launch_bounds__(512, 2) void gemm_ra_kernel(
    const uint16_t* __restrict__ At, const uint16_t* __restrict__ Bt,
    uint16_t* __restrict__ Ct, int Kt,
    const uint16_t* __restrict__ As_, const uint16_t* __restrict__ Bs_,
    uint16_t* __restrict__ Cs, int Ks,
    int V, int RT, int CT) {
  __shared__ __align__(16) uint16_t lds[65536];

  const int half = RT * CT;
  const uint16_t *A, *B;
  uint16_t* C;
  int K, bidx = blockIdx.x;
  if (bidx < half) { A = At; B = Bt; C = Ct; K = Kt; }
  else             { A = As_; B = Bs_; C = Cs; K = Ks; bidx -= half; }

  int L = ((half & 7) == 0) ? ((bidx & 7) * (half >> 3) + (bidx >> 3)) : bidx;
  const int rt = L % RT;
  const int ct = L / RT;
  const int row0 = rt * 256;
  const int col0 = ct * 256;

  const int i  = threadIdx.x;      // 0..511
  const int w  = i >> 6;
  const int l  = i & 63;
  const int wl = l & 15;
  const int kg = l >> 4;
  const int wr = w >> 2;           // wave row 0..1 (128 out rows)
  const int wc = w & 3;            // wave col 0..3 (64 out cols)

  const int nT = K >> 6;           // BK = 64

  // ---- staging: thread i loads granules i and i+512 per half-tile.
  // granule g: row r=g>>3, phys col=g&7; logical col = phys ^ (r&7).
  const int r0 = i >> 3;
  const int cph = i & 7;
  const int clog = cph ^ (r0 & 7);
  const uint16_t* aSrc = A + (size_t)(row0 + r0) * K + clog * 8;
  const uint16_t* bSrc = B + (size_t)(col0 + r0) * K + clog * 8;
  uint16_t* ldsu = lds;

#define GL(srcp, dstp)                                                     \
  __builtin_amdgcn_global_load_lds(                                        \
      (const __attribute__((address_space(1))) void*)(srcp),               \
      (__attribute__((address_space(3))) void*)(dstp), 16, 0, 0)

#define STAGE_H(basep, TT, HH, dof)                                        \
  do {                                                                     \
    const uint16_t* _s = basep + (size_t)(HH) * 128 * K + (size_t)(TT) * 64;\
    uint16_t* _d = ldsu + (((TT) & 1) * 32768) + (dof) + (HH) * 8192 + i * 8; \
    GL(_s, _d); GL(_s + (size_t)64 * K, _d + 4096);                        \
  } while (0)

#define STAGE(TT)                                                          \
  do {                                                                     \
    STAGE_H(aSrc, TT, 0, 0); STAGE_H(aSrc, TT, 1, 0);                      \
    STAGE_H(bSrc, TT, 0, 16384); STAGE_H(bSrc, TT, 1, 16384);              \
  } while (0)

  // ---- ds_read byte offsets (A-half = wr; B-half = wc>>1).
  // phys col = (slot*4+kg) ^ (wl&7).
  int offA[8][2], offB[4][2];
#pragma unroll
  for (int m = 0; m < 8; ++m) {
    const int rho = (m & 3) * 16 + wl;
    const int mh = m >> 2;
#pragma unroll
    for (int s = 0; s < 2; ++s)
      offA[m][s] = wr * 16384 + mh * 8192 + rho * 128 +
                   (((s * 4 + kg) ^ (wl & 7)) * 16);
  }
#pragma unroll
  for (int n = 0; n < 4; ++n) {
    const int sig = (wc & 1) * 64 + n * 16 + wl;
#pragma unroll
    for (int s = 0; s < 2; ++s)
      offB[n][s] = 32768 + (wc >> 1) * 16384 + sig * 128 +
                   (((s * 4 + kg) ^ (wl & 7)) * 16);
  }

  f32x4 acc[8][4] = {};
  bf16x8 A0[4], B0[4];

  // ---- prologue: stage tile0, drain, stage tile1, read ph0 frags
  STAGE(0);
  asm volatile("s_waitcnt vmcnt(0)" ::: "memory");
  __builtin_amdgcn_s_barrier();
  __builtin_amdgcn_sched_barrier(0);
  if (nT > 1) STAGE(1);
  {
    const char* bb = (const char*)lds;
#pragma unroll
    for (int m = 0; m < 4; ++m)
      A0[m] = *reinterpret_cast<const bf16x8*>(bb + offA[m][0]);
#pragma unroll
    for (int n = 0; n < 4; ++n)
      B0[n] = *reinterpret_cast<const bf16x8*>(bb + offB[n][0]);
  }

  for (int T = 0; T < nT; ++T) {
    const char* bb = (const char*)lds + (T & 1) * 65536;
    bf16x8 A1[4], A2[4], B1[4], A3[4], A0n[4], B0n[4];

    // ---------- ph0: issue A1 = A(mh1,s0); MFMA(A0,B0) -> acc[0..3]
#pragma unroll
    for (int m = 0; m < 4; ++m)
      A1[m] = *reinterpret_cast<const bf16x8*>(bb + offA[4 + m][0]);
    __builtin_amdgcn_sched_barrier(0);
    __builtin_amdgcn_s_setprio(1);
#pragma unroll
    for (int m = 0; m < 4; ++m)
#pragma unroll
      for (int n = 0; n < 4; ++n)
        acc[m][n] = __builtin_amdgcn_mfma_f32_16x16x32_bf16(
            A0[m], B0[n], acc[m][n], 0, 0, 0);
    __builtin_amdgcn_s_setprio(0);
    __builtin_amdgcn_sched_barrier(0);

    // ---------- ph1: issue A2 = A(mh0,s1), B1 = B(s1); MFMA(A1,B0) -> acc[4..7]
#pragma unroll
    for (int m = 0; m < 4; ++m)
      A2[m] = *reinterpret_cast<const bf16x8*>(bb + offA[m][1]);
#pragma unroll
    for (int n = 0; n < 4; ++n)
      B1[n] = *reinterpret_cast<const bf16x8*>(bb + offB[n][1]);
    __builtin_amdgcn_sched_barrier(0);
    __builtin_amdgcn_s_setprio(1);
#pragma unroll
    for (int m = 0; m < 4; ++m)
#pragma unroll
      for (int n = 0; n < 4; ++n)
        acc[4 + m][n] = __builtin_amdgcn_mfma_f32_16x16x32_bf16(
            A1[m], B0[n], acc[4 + m][n], 0, 0, 0);
    __builtin_amdgcn_s_setprio(0);
    __builtin_amdgcn_sched_barrier(0);

    // ---------- ph2: issue A3 = A(mh1,s1); MFMA(A2,B1) -> acc[0..3]
#pragma unroll
    for (int m = 0; m < 4; ++m)
      A3[m] = *reinterpret_cast<const bf16x8*>(bb + offA[4 + m][1]);
    __builtin_amdgcn_sched_barrier(0);
    __builtin_amdgcn_s_setprio(1);
#pragma unroll
    for (int m = 0; m < 4; ++m)
#pragma unroll
      for (int n = 0; n < 4; ++n)
        acc[m][n] = __builtin_amdgcn_mfma_f32_16x16x32_bf16(
            A2[m], B1[n], acc[m][n], 0, 0, 0);
    __builtin_amdgcn_s_setprio(0);
    __builtin_amdgcn_sched_barrier(0);

    // ---------- ph3 boundary: drain my reads of buf[T&1] (lgkm) and my
    // stage(T+1) loads (vmcnt); barrier => block-wide both hold; then
    // stage(T+2) into buf[T&1] and read-ahead tile T+1 ph0 from buf[(T+1)&1],
    // both overlapping MFMA(A3,B1).
    if (T + 1 < nT) {
      asm volatile("s_waitcnt lgkmcnt(0)" ::: "memory");
      asm volatile("s_waitcnt vmcnt(0)" ::: "memory");
      __builtin_amdgcn_s_barrier();
      __builtin_amdgcn_sched_barrier(0);
      if (T + 2 < nT) STAGE(T + 2);
      const char* bbn = (const char*)lds + ((T + 1) & 1) * 65536;
#pragma unroll
      for (int m = 0; m < 4; ++m)
        A0n[m] = *reinterpret_cast<const bf16x8*>(bbn + offA[m][0]);
#pragma unroll
      for (int n = 0; n < 4; ++n)
        B0n[n] = *reinterpret_cast<const bf16x8*>(bbn + offB[n][0]);
      __builtin_amdgcn_sched_barrier(0);
    }
    __builtin_amdgcn_s_setprio(1);
#pragma unroll
    for (int m = 0; m < 4; ++m)
#pragma unroll
      for (int n = 0; n < 4; ++n)
        acc[4 + m][n] = __builtin_amdgcn_mfma_f32_16x16x32_bf16(
            A3[m], B1[n], acc[4 + m][n], 0, 0, 0);
    __builtin_amdgcn_s_setprio(0);
    __builtin_amdgcn_sched_barrier(0);
    if (T + 1 < nT) {
#pragma unroll
      for (int m = 0; m < 4; ++m) A0[m] = A0n[m];
#pragma unroll
      for (int n = 0; n < 4; ++n) B0[n] = B0n[n];
    }
  }

  // ---- epilogue: C/D layout col=lane&15, row=(lane>>4)*4+reg
#pragma unroll
  for (int mg = 0; mg < 8; ++mg)
#pragma unroll
    for (int ng = 0; ng < 4; ++ng)
#pragma unroll
      for (int r = 0; r < 4; ++r) {
        const int row = row0 + wr * 128 + mg * 16 + kg * 4 + r;
        const int col = col0 + wc * 64 + ng * 16 + wl;
        __hip_bfloat16 bv = __float2bfloat16(acc[mg][ng][r]);
        C[(size_t)row * V + col] = *reinterpret_cast<const uint16_t*>(&bv);
      }
#undef STAGE
#undef STAGE_H
#undef GL
}

// ---------------------------------------------------------------- JSD rows
__device__ __forceinline__ void unpack8(uint4 v, float* f) {
  uint32_t w[4] = {v.x, v.y, v.z, v.w};
#pragma unroll
  for (int j = 0; j < 4; ++j) {
    union { uint32_t u; float x; } lo, hi;
    lo.u = (w[j] & 0xffffu) << 16;
    hi.u = w[j] & 0xffff0000u;
    f[2 * j] = lo.x;
    f[2 * j + 1] = hi.x;
  }
}

__device__ __forceinline__ float blockReduce(float v, bool isMax, float* sh) {
#pragma unroll
  for (int o = 32; o >= 1; o >>= 1) {
    float other = __shfl_xor(v, o, 64);
    v = isMax ? fmaxf(v, other) : (v + other);
  }
  const int w = threadIdx.x >> 6;
  __syncthreads();
  if ((threadIdx.x & 63) == 0) sh[w] = v;
  __syncthreads();
  float r = sh[0];
#pragma unroll
  for (int i = 1; i < 4; ++i) r = isMax ? fmaxf(r, sh[i]) : (r + sh[i]);
  return r;
}

__global__ __launch_bounds__(256) void jsd_rows_kernel(
    const uint16_t* __restrict__ SL, const uint16_t* __restrict__ TL,
    float* __restrict__ per_tok, int V) {
  __shared__ __align__(16) uint16_t rowS[32000];
  __shared__ __align__(16) uint16_t rowT[32000];
  __shared__ float red[4];

  const int t = threadIdx.x;
  const int row = blockIdx.x;
  const uint4* gS = reinterpret_cast<const uint4*>(SL + (size_t)row * V);
  const uint4* gT = reinterpret_cast<const uint4*>(TL + (size_t)row * V);
  uint4* lS = reinterpret_cast<uint4*>(rowS);
  uint4* lT = reinterpret_cast<uint4*>(rowT);
  const int nvec = V >> 3;  // 4000

  for (int i = t; i < nvec; i += 256) { lS[i] = gS[i]; lT[i] = gT[i]; }
  __syncthreads();

  float mS = -3.0e38f, mT = -3.0e38f;
  for (int i = t; i < nvec; i += 256) {
    float fs[8], ft[8];
    unpack8(lS[i], fs);
    unpack8(lT[i], ft);
#pragma unroll
    for (int j = 0; j < 8; ++j) { mS = fmaxf(mS, fs[j]); mT = fmaxf(mT, ft[j]); }
  }
  mS = blockReduce(mS, true, red);
  mT = blockReduce(mT, true, red);

  float sS = 0.f, sT = 0.f;
  for (int i = t; i < nvec; i += 256) {
    float fs[8], ft[8];
    unpack8(lS[i], fs);
    unpack8(lT[i], ft);
#pragma unroll
    for (int j = 0; j < 8; ++j) { sS += __expf(fs[j] - mS); sT += __expf(ft[j] - mT); }
  }
  sS = blockReduce(sS, false, red);
  sT = blockReduce(sT, false, red);
  const float lseS = mS + __logf(sS);
  const float lseT = mT + __logf(sT);

  float acc = 0.f;
  for (int i = t; i < nvec; i += 256) {
    float fs[8], ft[8];
    unpack8(lS[i], fs);
    unpack8(lT[i], ft);
#pragma unroll
    for (int j = 0; j < 8; ++j) {
      const float lq = fs[j] - lseS;
      const float lp = ft[j] - lseT;
      const float q = __expf(lq);
      const float p = __expf(lp);
      const float m = BETA * p + (1.f - BETA) * q;
      const float lm = __logf(m);
      acc += BETA * p * (lp - lm) + (1.f - BETA) * q * (lq - lm);
    }
  }
  acc = blockReduce(acc, false, red);
  if (t == 0) per_tok[row] = acc;
}

// ---------------------------------------------------------------- finalize
__global__ __launch_bounds__(256) void finalize_kernel(
    const float* __restrict__ per_tok, const int* __restrict__ tgt,
    float* __restrict__ out, int N) {
  __shared__ float redf[4];
  __shared__ int redi[4];
  float s = 0.f;
  int c = 0;
  for (int i = threadIdx.x; i < N; i += 256) {
    if (tgt[i] != IGNORE_INDEX) { s += per_tok[i]; c += 1; }
  }
#pragma unroll
  for (int o = 32; o >= 1; o >>= 1) {
    s += __shfl_xor(s, o, 64);
    c += __shfl_xor(c, o, 64);
  }
  const int w = threadIdx.x >> 6;
  if ((threadIdx.x & 63) == 0) { redf[w] = s; redi[w] = c; }
  __syncthreads();
  if (threadIdx.x == 0) {
    float st = 0.f;
    int ct = 0;
#pragma unroll
    for (int i = 0; i < 4; ++i) { st += redf[i]; ct += redi[i]; }
    out[0] = st / (float)(ct > 0 ? ct : 1);
  }
}

// ---------------------------------------------------------------- launch
extern "C" void kernel_launch(void* const* d_in, const int* in_sizes, int n_in,
                              void* d_out, int out_size, void* d_ws, size_t ws_size,
                              hipStream_t stream) {
  const float* student = (const float*)d_in[0];
  const float* W_s     = (const float*)d_in[1];
  const float* teacher = (const float*)d_in[2];
  const float* W_t     = (const float*)d_in[3];
  const int*   target  = (const int*)d_in[4];

  const int N  = in_sizes[4];            // 2048
  const int Hs = in_sizes[0] / N;        // 2048
  const int Ht = in_sizes[2] / N;        // 4096
  const int V  = in_sizes[1] / Hs;       // 32000

  char* ws = (char*)d_ws;
  size_t off = 0;
  auto alloc = [&](size_t bytes) -> void* {
    void* p = ws + off;
    off += (bytes + 255) & ~(size_t)255;
    return p;
  };
  uint16_t* Sbf  = (uint16_t*)alloc((size_t)N * Hs * 2);
  uint16_t* Wsbf = (uint16_t*)alloc((size_t)V * Hs * 2);
  uint16_t* Tbf  = (uint16_t*)alloc((size_t)N * Ht * 2);
  uint16_t* Wtbf = (uint16_t*)alloc((size_t)V * Ht * 2);
  uint16_t* slog = (uint16_t*)alloc((size_t)N * V * 2);
  uint16_t* tlog = (uint16_t*)alloc((size_t)N * V * 2);
  float* per_tok = (float*)alloc((size_t)N * sizeof(float));
  (void)ws_size;  // total ~681 MB

  f32_to_bf16_kernel<<<1024, 256, 0, stream>>>(student, Sbf, N * Hs);
  f32_to_bf16_kernel<<<2048, 256, 0, stream>>>(W_s, Wsbf, V * Hs);
  f32_to_bf16_kernel<<<1024, 256, 0, stream>>>(teacher, Tbf, N * Ht);
  f32_to_bf16_kernel<<<2048, 256, 0, stream>>>(W_t, Wtbf, V * Ht);

  const int RT = N / 256;   // 8
  const int CT = V / 256;   // 125
  // merged launch: teacher blocks first, student backfills the tail
  gemm_ra_kernel<<<2 * RT * CT, 512, 0, stream>>>(
      Tbf, Wtbf, tlog, Ht, Sbf, Wsbf, slog, Hs, V, RT, CT);

  jsd_rows_kernel<<<N, 256, 0, stream>>>(slog, tlog, per_tok, V);
  finalize_kernel<<<1, 256, 0, stream>>>(per_tok, target, (float*)d_out, N);
}

// Round 7
// 1047.495 us; speedup vs baseline: 1.4695x; 1.4695x over previous
//
#include <hip/hip_runtime.h>
#include <hip/hip_bf16.h>
#include <stdint.h>

#define BETA 0.5f
#define IGNORE_INDEX (-100)

typedef short bf16x8 __attribute__((ext_vector_type(8)));
typedef float f32x4 __attribute__((ext_vector_type(4)));

// ---------------------------------------------------------------- converts
__global__ __launch_bounds__(256) void f32_to_bf16_kernel(
    const float* __restrict__ in, uint16_t* __restrict__ out, int n) {
  int i = (blockIdx.x * blockDim.x + threadIdx.x) * 4;
  const int stride = gridDim.x * blockDim.x * 4;
  for (; i < n; i += stride) {
    float4 v = *reinterpret_cast<const float4*>(in + i);
    __hip_bfloat16 b0 = __float2bfloat16(v.x);
    __hip_bfloat16 b1 = __float2bfloat16(v.y);
    __hip_bfloat16 b2 = __float2bfloat16(v.z);
    __hip_bfloat16 b3 = __float2bfloat16(v.w);
    ushort4 o;
    o.x = *reinterpret_cast<const uint16_t*>(&b0);
    o.y = *reinterpret_cast<const uint16_t*>(&b1);
    o.z = *reinterpret_cast<const uint16_t*>(&b2);
    o.w = *reinterpret_cast<const uint16_t*>(&b3);
    *reinterpret_cast<ushort4*>(out + i) = o;
  }
}

// ---------------------------------------------------------------- GEMM (NT)
// C[n][v] = sum_k A[n][k]*B[v][k].  256x256 tile, BK=64, 8 waves (2Mx4N).
// ONE barrier per K-tile (r3's overlap structure) + conflict-free granule
// XOR layout (r5).  Within a tile: 4 read/MFMA chunks with NO barriers and
// NO asm waits -- compiler inserts exact per-dep lgkmcnt, and the 2
// waves/SIMD drift freely so LDS service overlaps MFMA.  Race-safety: every
// ds_read is consumed by an MFMA in the same tile => retired before that
// wave's boundary barrier => post-barrier stage into that buffer is safe.
// Boundary: counted vmcnt(4) (leaves B(T+2) in flight), s_barrier,
// sched_barrier.  Stages: A(T+1) halves at chunk 1/2 (other buffer);
// B(T+2) at chunk 4 (current buffer, r5-proven issue point).
// LDS: 2 buf x (A 32K + B 32K) = 128 KiB.
// Merged launch: blocks [0,half) = teacher, [half,2*half) = student.

__global__ __launch_bounds__(512, 2) void gemm_ov_kernel(
    const uint16_t* __restrict__ At, const uint16_t* __restrict__ Bt,
    uint16_t* __restrict__ Ct, int Kt,
    const uint16_t* __restrict__ As_, const uint16_t* __restrict__ Bs_,
    uint16_t* __restrict__ Cs, int Ks,
    int V, int RT, int CT) {
  __shared__ __align__(16) uint16_t lds[65536];

  const int half = RT * CT;
  const uint16_t *A, *B;
  uint16_t* C;
  int K, bidx = blockIdx.x;
  if (bidx < half) { A = At; B = Bt; C = Ct; K = Kt; }
  else             { A = As_; B = Bs_; C = Cs; K = Ks; bidx -= half; }

  int L = ((half & 7) == 0) ? ((bidx & 7) * (half >> 3) + (bidx >> 3)) : bidx;
  const int rt = L % RT;
  const int ct = L / RT;
  const int row0 = rt * 256;
  const int col0 = ct * 256;

  const int i  = threadIdx.x;      // 0..511
  const int w  = i >> 6;
  const int l  = i & 63;
  const int wl = l & 15;
  const int kg = l >> 4;
  const int wr = w >> 2;           // wave row 0..1 (128 out rows)
  const int wc = w & 3;            // wave col 0..3 (64 out cols)

  const int nT = K >> 6;           // BK = 64

  // ---- staging: thread i loads granules i and i+512 per half-tile.
  // granule g: row r=g>>3, phys col=g&7; logical col = phys ^ (r&7).
  const int r0 = i >> 3;
  const int cph = i & 7;
  const int clog = cph ^ (r0 & 7);
  const uint16_t* aSrc = A + (size_t)(row0 + r0) * K + clog * 8;
  const uint16_t* bSrc = B + (size_t)(col0 + r0) * K + clog * 8;
  uint16_t* ldsu = lds;

#define GL(srcp, dstp)                                                     \
  __builtin_amdgcn_global_load_lds(                                        \
      (const __attribute__((address_space(1))) void*)(srcp),               \
      (__attribute__((address_space(3))) void*)(dstp), 16, 0, 0)

#define STAGE_A(TT, HH)                                                    \
  do {                                                                     \
    const uint16_t* _s = aSrc + (size_t)(HH) * 128 * K + (size_t)(TT) * 64;\
    uint16_t* _d = ldsu + (((TT) & 1) * 32768) + (HH) * 8192 + i * 8;      \
    GL(_s, _d); GL(_s + (size_t)64 * K, _d + 4096);                        \
  } while (0)

#define STAGE_B(TT, HH)                                                    \
  do {                                                                     \
    const uint16_t* _s = bSrc + (size_t)(HH) * 128 * K + (size_t)(TT) * 64;\
    uint16_t* _d = ldsu + (((TT) & 1) * 32768) + 16384 + (HH) * 8192 + i * 8; \
    GL(_s, _d); GL(_s + (size_t)64 * K, _d + 4096);                        \
  } while (0)

  // ---- ds_read byte offsets (A-half = wr; B-half = wc>>1).
  // phys col = (slot*4+kg) ^ (wl&7).
  int offA[8][2], offB[4][2];
#pragma unroll
  for (int m = 0; m < 8; ++m) {
    const int rho = (m & 3) * 16 + wl;
    const int mh = m >> 2;
#pragma unroll
    for (int s = 0; s < 2; ++s)
      offA[m][s] = wr * 16384 + mh * 8192 + rho * 128 +
                   (((s * 4 + kg) ^ (wl & 7)) * 16);
  }
#pragma unroll
  for (int n = 0; n < 4; ++n) {
    const int sig = (wc & 1) * 64 + n * 16 + wl;
#pragma unroll
    for (int s = 0; s < 2; ++s)
      offB[n][s] = 32768 + (wc >> 1) * 16384 + sig * 128 +
                   (((s * 4 + kg) ^ (wl & 7)) * 16);
  }

  f32x4 acc[8][4] = {};
  bf16x8 af[4], bf[4], ag[4];

  // ---- prologue: tile0 all halves + tile1 B halves; drain tile0
  STAGE_A(0, 0); STAGE_A(0, 1); STAGE_B(0, 0); STAGE_B(0, 1);
  if (nT > 1) {
    STAGE_B(1, 0); STAGE_B(1, 1);
    asm volatile("s_waitcnt vmcnt(4)" ::: "memory");
  } else {
    asm volatile("s_waitcnt vmcnt(0)" ::: "memory");
  }
  __builtin_amdgcn_s_barrier();
  __builtin_amdgcn_sched_barrier(0);

  for (int T = 0; T < nT; ++T) {
    const char* bb = (const char*)lds + (T & 1) * 65536;
    const bool stg1 = (T + 1) < nT;
    const bool stg2 = (T + 2) < nT;

    // ---------- chunk 1: read A(mh0,s0)+B(s0); stage A0(T+1); MFMA m0..3 s0
#pragma unroll
    for (int m = 0; m < 4; ++m)
      af[m] = *reinterpret_cast<const bf16x8*>(bb + offA[m][0]);
#pragma unroll
    for (int n = 0; n < 4; ++n)
      bf[n] = *reinterpret_cast<const bf16x8*>(bb + offB[n][0]);
    if (stg1) STAGE_A(T + 1, 0);
    __builtin_amdgcn_s_setprio(1);
#pragma unroll
    for (int m = 0; m < 4; ++m)
#pragma unroll
      for (int n = 0; n < 4; ++n)
        acc[m][n] = __builtin_amdgcn_mfma_f32_16x16x32_bf16(
            af[m], bf[n], acc[m][n], 0, 0, 0);
    __builtin_amdgcn_s_setprio(0);

    // ---------- chunk 2: read A(mh1,s0); stage A1(T+1); MFMA m4..7 s0
#pragma unroll
    for (int m = 0; m < 4; ++m)
      ag[m] = *reinterpret_cast<const bf16x8*>(bb + offA[4 + m][0]);
    if (stg1) STAGE_A(T + 1, 1);
    __builtin_amdgcn_s_setprio(1);
#pragma unroll
    for (int m = 0; m < 4; ++m)
#pragma unroll
      for (int n = 0; n < 4; ++n)
        acc[4 + m][n] = __builtin_amdgcn_mfma_f32_16x16x32_bf16(
            ag[m], bf[n], acc[4 + m][n], 0, 0, 0);
    __builtin_amdgcn_s_setprio(0);

    // ---------- chunk 3: read A(mh0,s1)+B(s1); MFMA m0..3 s1
#pragma unroll
    for (int m = 0; m < 4; ++m)
      af[m] = *reinterpret_cast<const bf16x8*>(bb + offA[m][1]);
#pragma unroll
    for (int n = 0; n < 4; ++n)
      bf[n] = *reinterpret_cast<const bf16x8*>(bb + offB[n][1]);
    __builtin_amdgcn_s_setprio(1);
#pragma unroll
    for (int m = 0; m < 4; ++m)
#pragma unroll
      for (int n = 0; n < 4; ++n)
        acc[m][n] = __builtin_amdgcn_mfma_f32_16x16x32_bf16(
            af[m], bf[n], acc[m][n], 0, 0, 0);
    __builtin_amdgcn_s_setprio(0);

    // ---------- chunk 4: read A(mh1,s1); stage B0+B1(T+2); MFMA m4..7 s1
#pragma unroll
    for (int m = 0; m < 4; ++m)
      ag[m] = *reinterpret_cast<const bf16x8*>(bb + offA[4 + m][1]);
    if (stg2) { STAGE_B(T + 2, 0); STAGE_B(T + 2, 1); }
    __builtin_amdgcn_s_setprio(1);
#pragma unroll
    for (int m = 0; m < 4; ++m)
#pragma unroll
      for (int n = 0; n < 4; ++n)
        acc[4 + m][n] = __builtin_amdgcn_mfma_f32_16x16x32_bf16(
            ag[m], bf[n], acc[4 + m][n], 0, 0, 0);
    __builtin_amdgcn_s_setprio(0);

    // ---------- boundary: counted vmcnt (never 0 in steady state), barrier
    if (stg2) {
      asm volatile("s_waitcnt vmcnt(4)" ::: "memory");
    } else {
      asm volatile("s_waitcnt vmcnt(0)" ::: "memory");
    }
    __builtin_amdgcn_s_barrier();
    __builtin_amdgcn_sched_barrier(0);
  }

  // ---- epilogue: C/D layout col=lane&15, row=(lane>>4)*4+reg
#pragma unroll
  for (int mg = 0; mg < 8; ++mg)
#pragma unroll
    for (int ng = 0; ng < 4; ++ng)
#pragma unroll
      for (int r = 0; r < 4; ++r) {
        const int row = row0 + wr * 128 + mg * 16 + kg * 4 + r;
        const int col = col0 + wc * 64 + ng * 16 + wl;
        __hip_bfloat16 bv = __float2bfloat16(acc[mg][ng][r]);
        C[(size_t)row * V + col] = *reinterpret_cast<const uint16_t*>(&bv);
      }
#undef STAGE_A
#undef STAGE_B
#undef GL
}

// ---------------------------------------------------------------- JSD rows
__device__ __forceinline__ void unpack8(uint4 v, float* f) {
  uint32_t w[4] = {v.x, v.y, v.z, v.w};
#pragma unroll
  for (int j = 0; j < 4; ++j) {
    union { uint32_t u; float x; } lo, hi;
    lo.u = (w[j] & 0xffffu) << 16;
    hi.u = w[j] & 0xffff0000u;
    f[2 * j] = lo.x;
    f[2 * j + 1] = hi.x;
  }
}

__device__ __forceinline__ float blockReduce(float v, bool isMax, float* sh) {
#pragma unroll
  for (int o = 32; o >= 1; o >>= 1) {
    float other = __shfl_xor(v, o, 64);
    v = isMax ? fmaxf(v, other) : (v + other);
  }
  const int w = threadIdx.x >> 6;
  __syncthreads();
  if ((threadIdx.x & 63) == 0) sh[w] = v;
  __syncthreads();
  float r = sh[0];
#pragma unroll
  for (int i = 1; i < 4; ++i) r = isMax ? fmaxf(r, sh[i]) : (r + sh[i]);
  return r;
}

__global__ __launch_bounds__(256) void jsd_rows_kernel(
    const uint16_t* __restrict__ SL, const uint16_t* __restrict__ TL,
    float* __restrict__ per_tok, int V) {
  __shared__ __align__(16) uint16_t rowS[32000];
  __shared__ __align__(16) uint16_t rowT[32000];
  __shared__ float red[4];

  const int t = threadIdx.x;
  const int row = blockIdx.x;
  const uint4* gS = reinterpret_cast<const uint4*>(SL + (size_t)row * V);
  const uint4* gT = reinterpret_cast<const uint4*>(TL + (size_t)row * V);
  uint4* lS = reinterpret_cast<uint4*>(rowS);
  uint4* lT = reinterpret_cast<uint4*>(rowT);
  const int nvec = V >> 3;  // 4000

  for (int i = t; i < nvec; i += 256) { lS[i] = gS[i]; lT[i] = gT[i]; }
  __syncthreads();

  float mS = -3.0e38f, mT = -3.0e38f;
  for (int i = t; i < nvec; i += 256) {
    float fs[8], ft[8];
    unpack8(lS[i], fs);
    unpack8(lT[i], ft);
#pragma unroll
    for (int j = 0; j < 8; ++j) { mS = fmaxf(mS, fs[j]); mT = fmaxf(mT, ft[j]); }
  }
  mS = blockReduce(mS, true, red);
  mT = blockReduce(mT, true, red);

  float sS = 0.f, sT = 0.f;
  for (int i = t; i < nvec; i += 256) {
    float fs[8], ft[8];
    unpack8(lS[i], fs);
    unpack8(lT[i], ft);
#pragma unroll
    for (int j = 0; j < 8; ++j) { sS += __expf(fs[j] - mS); sT += __expf(ft[j] - mT); }
  }
  sS = blockReduce(sS, false, red);
  sT = blockReduce(sT, false, red);
  const float lseS = mS + __logf(sS);
  const float lseT = mT + __logf(sT);

  float acc = 0.f;
  for (int i = t; i < nvec; i += 256) {
    float fs[8], ft[8];
    unpack8(lS[i], fs);
    unpack8(lT[i], ft);
#pragma unroll
    for (int j = 0; j < 8; ++j) {
      const float lq = fs[j] - lseS;
      const float lp = ft[j] - lseT;
      const float q = __expf(lq);
      const float p = __expf(lp);
      const float m = BETA * p + (1.f - BETA) * q;
      const float lm = __logf(m);
      acc += BETA * p * (lp - lm) + (1.f - BETA) * q * (lq - lm);
    }
  }
  acc = blockReduce(acc, false, red);
  if (t == 0) per_tok[row] = acc;
}

// ---------------------------------------------------------------- finalize
__global__ __launch_bounds__(256) void finalize_kernel(
    const float* __restrict__ per_tok, const int* __restrict__ tgt,
    float* __restrict__ out, int N) {
  __shared__ float redf[4];
  __shared__ int redi[4];
  float s = 0.f;
  int c = 0;
  for (int i = threadIdx.x; i < N; i += 256) {
    if (tgt[i] != IGNORE_INDEX) { s += per_tok[i]; c += 1; }
  }
#pragma unroll
  for (int o = 32; o >= 1; o >>= 1) {
    s += __shfl_xor(s, o, 64);
    c += __shfl_xor(c, o, 64);
  }
  const int w = threadIdx.x >> 6;
  if ((threadIdx.x & 63) == 0) { redf[w] = s; redi[w] = c; }
  __syncthreads();
  if (threadIdx.x == 0) {
    float st = 0.f;
    int ct = 0;
#pragma unroll
    for (int i = 0; i < 4; ++i) { st += redf[i]; ct += redi[i]; }
    out[0] = st / (float)(ct > 0 ? ct : 1);
  }
}

// ---------------------------------------------------------------- launch
extern "C" void kernel_launch(void* const* d_in, const int* in_sizes, int n_in,
                              void* d_out, int out_size, void* d_ws, size_t ws_size,
                              hipStream_t stream) {
  const float* student = (const float*)d_in[0];
  const float* W_s     = (const float*)d_in[1];
  const float* teacher = (const float*)d_in[2];
  const float* W_t     = (const float*)d_in[3];
  const int*   target  = (const int*)d_in[4];

  const int N  = in_sizes[4];            // 2048
  const int Hs = in_sizes[0] / N;        // 2048
  const int Ht = in_sizes[2] / N;        // 4096
  const int V  = in_sizes[1] / Hs;       // 32000

  char* ws = (char*)d_ws;
  size_t off = 0;
  auto alloc = [&](size_t bytes) -> void* {
    void* p = ws + off;
    off += (bytes + 255) & ~(size_t)255;
    return p;
  };
  uint16_t* Sbf  = (uint16_t*)alloc((size_t)N * Hs * 2);
  uint16_t* Wsbf = (uint16_t*)alloc((size_t)V * Hs * 2);
  uint16_t* Tbf  = (uint16_t*)alloc((size_t)N * Ht * 2);
  uint16_t* Wtbf = (uint16_t*)alloc((size_t)V * Ht * 2);
  uint16_t* slog = (uint16_t*)alloc((size_t)N * V * 2);
  uint16_t* tlog = (uint16_t*)alloc((size_t)N * V * 2);
  float* per_tok = (float*)alloc((size_t)N * sizeof(float));
  (void)ws_size;  // total ~681 MB

  f32_to_bf16_kernel<<<1024, 256, 0, stream>>>(student, Sbf, N * Hs);
  f32_to_bf16_kernel<<<2048, 256, 0, stream>>>(W_s, Wsbf, V * Hs);
  f32_to_bf16_kernel<<<1024, 256, 0, stream>>>(teacher, Tbf, N * Ht);
  f32_to_bf16_kernel<<<2048, 256, 0, stream>>>(W_t, Wtbf, V * Ht);

  const int RT = N / 256;   // 8
  const int CT = V / 256;   // 125
  // merged launch: teacher blocks first, student backfills the tail
  gemm_ov_kernel<<<2 * RT * CT, 512, 0, stream>>>(
      Tbf, Wtbf, tlog, Ht, Sbf, Wsbf, slog, Hs, V, RT, CT);

  jsd_rows_kernel<<<N, 256, 0, stream>>>(slog, tlog, per_tok, V);
  finalize_kernel<<<1, 256, 0, stream>>>(per_tok, target, (float*)d_out, N);
}